// Round 15
// baseline (81844.537 us; speedup 1.0000x reference)
//
#include <hip/hip_runtime.h>
#include <cstdint>
#include <cfloat>
#include <cmath>

#define NB 64
#define LL 2048
#define HH 512
#define VV 34
#define TT 600
#define BLKT 512
#define GRID 256
#define GBLK 32     // blocks per group
#define BSTRIDE 544 // per-group barrier region (ints): 32 arrival slots x16 + release

typedef unsigned long long ull;

// JAX threefry_partitionable (default since jax 0.4.36): bits = o0 ^ o1. VERIFIED round 2.
#define PARTITIONABLE 1

// Coherence-point (cross-XCD-safe) data path: bypasses L1/L2; no fences needed.
#define LDC(p)    __hip_atomic_load((p), __ATOMIC_RELAXED, __HIP_MEMORY_SCOPE_AGENT)
#define STC(p,v)  __hip_atomic_store((p), (v), __ATOMIC_RELAXED, __HIP_MEMORY_SCOPE_AGENT)

__device__ __forceinline__ float sigm_(float x){ return 1.0f/(1.0f+expf(-x)); }
__device__ __forceinline__ unsigned rotl_(unsigned x, int r){ return (x<<r)|(x>>(32-r)); }
__device__ __forceinline__ ull rtclk(){ return __builtin_amdgcn_s_memrealtime(); }

// Threefry-2x32, 20 rounds, exactly JAX's schedule.
__device__ __forceinline__ void tf2x32_(unsigned k0, unsigned k1, unsigned x0, unsigned x1,
                                        unsigned &o0, unsigned &o1){
  unsigned ks2 = k0 ^ k1 ^ 0x1BD11BDAu;
  x0 += k0; x1 += k1;
  x0+=x1; x1=rotl_(x1,13); x1^=x0;
  x0+=x1; x1=rotl_(x1,15); x1^=x0;
  x0+=x1; x1=rotl_(x1,26); x1^=x0;
  x0+=x1; x1=rotl_(x1, 6); x1^=x0;
  x0+=k1; x1+=ks2+1u;
  x0+=x1; x1=rotl_(x1,17); x1^=x0;
  x0+=x1; x1=rotl_(x1,29); x1^=x0;
  x0+=x1; x1=rotl_(x1,16); x1^=x0;
  x0+=x1; x1=rotl_(x1,24); x1^=x0;
  x0+=ks2; x1+=k0+2u;
  x0+=x1; x1=rotl_(x1,13); x1^=x0;
  x0+=x1; x1=rotl_(x1,15); x1^=x0;
  x0+=x1; x1=rotl_(x1,26); x1^=x0;
  x0+=x1; x1=rotl_(x1, 6); x1^=x0;
  x0+=k0; x1+=k1+3u;
  x0+=x1; x1=rotl_(x1,17); x1^=x0;
  x0+=x1; x1=rotl_(x1,29); x1^=x0;
  x0+=x1; x1=rotl_(x1,16); x1^=x0;
  x0+=x1; x1=rotl_(x1,24); x1^=x0;
  x0+=k1; x1+=ks2+4u;
  x0+=x1; x1=rotl_(x1,13); x1^=x0;
  x0+=x1; x1=rotl_(x1,15); x1^=x0;
  x0+=x1; x1=rotl_(x1,26); x1^=x0;
  x0+=x1; x1=rotl_(x1, 6); x1^=x0;
  x0+=ks2; x1+=k0+5u;
  o0 = x0; o1 = x1;
}

// Gumbel sample + argmax write. tid<34 path.
__device__ __forceinline__ void gumbel_emit_(int tid, int bb, int t, float* sZ,
                                             int* yv, int* out){
  if (tid < 34){
    unsigned kk0, kk1; tf2x32_(0u, 42u, 0u, (unsigned)t, kk0, kk1);
    int idx = bb*34 + tid;
    unsigned o0, o1, bits;
#if PARTITIONABLE
    tf2x32_(kk0, kk1, 0u, (unsigned)idx, o0, o1);
    bits = o0 ^ o1;
#else
    if (idx < 1088){ tf2x32_(kk0, kk1, (unsigned)idx, (unsigned)(idx+1088), o0, o1); bits = o0; }
    else           { tf2x32_(kk0, kk1, (unsigned)(idx-1088), (unsigned)idx, o0, o1); bits = o1; }
#endif
    float f = __uint_as_float((bits>>9) | 0x3f800000u) - 1.0f;
    float u = fmaxf(f, 1.17549435e-38f);
    sZ[tid] += -logf(-logf(u));
  }
  __syncthreads();
  if (tid == 0){
    float best = sZ[0]; int bi = 0;
    for (int v2=1; v2<34; v2++){ if (sZ[v2] > best){ best = sZ[v2]; bi = v2; } }
    STC(&yv[bb], bi);
    STC(&out[bb*TT + t], bi);
  }
}

// ============================================================================
// Verified R14 kernel (grid 256, 32/group, LPT, leader-poll barrier)
// + barrier-wait exfiltration through WRITE_SIZE (zero extra workspace)
// ============================================================================
__global__ __launch_bounds__(BLKT, 2) void speller_kernel_g32(
    const float* __restrict__ seq, const int* __restrict__ slen,
    const float* __restrict__ Ech, const float* __restrict__ Wkey,
    const float* __restrict__ Wval, const float* __restrict__ bval,
    const float* __restrict__ Wih, const float* __restrict__ Whh,
    const float* __restrict__ bih, const float* __restrict__ bhh,
    const float* __restrict__ Wcdn, const float* __restrict__ bcdn,
    int* __restrict__ out, float* __restrict__ ws, int MS, int CH)
{
  const int tid = threadIdx.x;
  const int bid = blockIdx.x;
  const int grp = bid & 7;         // group ~ XCD round-robin (perf heuristic only)
  const int li  = bid >> 3;        // 0..31

  float* h0   = ws;
  float* h1   = h0 + NB*HH;
  float* qt   = h1 + NB*HH;
  float* ctx  = qt + NB*HH;
  float* pm   = ctx + NB*HH;
  float* ps   = pm + NB*MS;
  float* pacc = ps + NB*MS;
  int*   iw   = (int*)(pacc + (size_t)NB*MS*HH);
  int*   yv   = iw;                 // [64]
  int*   bar  = iw + 64;            // [8*BSTRIDE] zeroed per launch

  __shared__ float sX[24*516];
  __shared__ float sRed[8*8*64];
  __shared__ float sGate[512];
  __shared__ float sAcc[8*512];
  __shared__ float sQt[512];
  __shared__ float sHb[512];
  __shared__ float sWm[8], sWs[8], sWf[8];
  __shared__ float sEb[512], sHs[512], sCt[512];
  __shared__ float sP[34*8];
  __shared__ float sZ[34];
  __shared__ float sAm[32], sAs[32], sAf[32];
  __shared__ float sSc[2];
  __shared__ int   sYv[8], sLen[8], sPref[9], sMap[8];
  __shared__ ull   sWT;

  float creg = 0.f;
  int epoch = 0;
  ull wtick = 0;          // tid0: total barrier wait (realtime ticks) inside t-loop
  bool measure = false;

  // ---- RMW-free leader-poll group barrier (verified R14) + optional timing ----
  auto gbar = [&](){
    __syncthreads();
    epoch++;
    if (tid == 0){
      ull t0 = measure ? rtclk() : 0;
      STC(&bar[grp*BSTRIDE + li*16], epoch);
      if (li == 0){
        // leader: tid0 polls all 32 slots (serial scan kept on tid0 only in
        // the li==0 branch below via lanes — preserved structure from R14)
      }
      if (li != 0){
        while (LDC(&bar[grp*BSTRIDE + 512]) < epoch)
          __builtin_amdgcn_s_sleep(1);
      }
      if (measure && li != 0) wtick += rtclk() - t0;
    }
    if (li == 0){
      ull t0 = (measure && tid == 0) ? rtclk() : 0;
      if (tid < 32){
        while (LDC(&bar[grp*BSTRIDE + tid*16]) < epoch)
          __builtin_amdgcn_s_sleep(1);
      }
      if (tid == 0){
        STC(&bar[grp*BSTRIDE + 512], epoch);   // release word
        if (measure) wtick += rtclk() - t0;
      }
    }
    __syncthreads();
  };

  // ---- deterministic LPT batch->group assignment (capacity 8), per-block redundant ----
  if (tid == 0){
    int ln[64]; unsigned char used[64];
    int load[8], cnt[8];
    for (int i=0;i<64;i++){
      int l = slen[i]; if (l<1) l=1; if (l>LL) l=LL;
      ln[i] = l; used[i] = 0;
    }
    for (int g2=0; g2<8; g2++){ load[g2]=0; cnt[g2]=0; }
    for (int it=0; it<64; it++){
      int bi = -1, bl = -1;
      for (int i=0;i<64;i++) if (!used[i] && ln[i] > bl){ bl = ln[i]; bi = i; }
      used[bi] = 1;
      int gi = -1, gl = 0x7fffffff;
      for (int g2=0; g2<8; g2++) if (cnt[g2] < 8 && load[g2] < gl){ gl = load[g2]; gi = g2; }
      if (gi == grp) sMap[cnt[gi]] = bi;
      load[gi] += bl; cnt[gi]++;
    }
  }
  __syncthreads();

  // ---- group-local init ----
  if (li < 8){
    int bb = sMap[li];
    STC(&h0[(size_t)bb*HH + tid], 0.f);
    STC(&h1[(size_t)bb*HH + tid], 0.f);
    STC(&qt[(size_t)bb*HH + tid], 0.f);
  }
  if (li == 8 && tid < 8) STC(&yv[sMap[tid]], 0);   // SOS

  // ================= phases (FP order bit-exact vs verified R10/R13/R14) =================

  auto phaseA = [&](const float* hr, float* hw){
    if (tid < 8) sYv[tid] = LDC(&yv[sMap[tid]]);
    __syncthreads();
    #pragma unroll
    for (int i = 0; i < 24; i++){
      int b = i & 7, s = i >> 3;
      int bb = sMap[b];
      float v;
      if (s == 0)      v = Ech[(size_t)sYv[b]*HH + tid];
      else if (s == 1) v = LDC(&ctx[(size_t)bb*HH + tid]);
      else             v = LDC(&hr[(size_t)bb*HH + tid]);
      sX[i*516 + tid] = v;
    }
    __syncthreads();
    const int w = tid >> 6, lane = tid & 63, rr = lane >> 3, bb = lane & 7;
    float acc[8];
    #pragma unroll
    for (int o=0;o<8;o++) acc[o]=0.f;
    for (int kt = 0; kt < 12; kt++){
      const int sec = (kt < 4) ? 0 : (kt < 8) ? 1 : 2;
      const int cb4 = (kt & 3) * 128;
      #pragma unroll
      for (int it = 0; it < 4; it++){
        int kkb = w*16 + it*4;
        const float* xp = &sX[(sec*8 + bb)*516 + cb4 + kkb];
        float x0 = xp[0], x1 = xp[1], x2 = xp[2], x3 = xp[3];
        #pragma unroll
        for (int o = 0; o < 8; o++){
          int jl = o*8 + rr;
          int j  = (jl >> 4)*512 + li*16 + (jl & 15);
          const float* wp = (kt < 8) ? Wih + (size_t)j*1024 + kt*128 + kkb
                                     : Whh + (size_t)j*512  + (kt-8)*128 + kkb;
          float4 wv = *(const float4*)wp;
          acc[o] += wv.x*x0; acc[o] += wv.y*x1;
          acc[o] += wv.z*x2; acc[o] += wv.w*x3;
        }
      }
    }
    __syncthreads();
    #pragma unroll
    for (int o=0;o<8;o++) sRed[(w*8+o)*64 + lane] = acc[o];
    __syncthreads();
    {
      int jl = tid >> 3, b2 = tid & 7;
      int o = jl >> 3, rr2 = jl & 7;
      int j = (jl >> 4)*512 + li*16 + (jl & 15);
      float g = bih[j] + bhh[j];
      #pragma unroll
      for (int w2 = 0; w2 < 8; w2++) g += sRed[(w2*8+o)*64 + rr2*8 + b2];
      sGate[jl*8 + b2] = g;
    }
    __syncthreads();
    if (tid < 128){
      int kp = tid >> 3, b3 = tid & 7;
      float gi = sGate[(0*16+kp)*8 + b3];
      float gf = sGate[(1*16+kp)*8 + b3];
      float gg = sGate[(2*16+kp)*8 + b3];
      float go = sGate[(3*16+kp)*8 + b3];
      float cn = sigm_(gf)*creg + sigm_(gi)*tanhf(gg);
      creg = cn;
      STC(&hw[(size_t)sMap[b3]*HH + li*16 + kp], sigm_(go)*tanhf(cn));
    }
  };

  auto phaseB = [&](const float* hw){
    int bb = sMap[li >> 2];
    int c0 = (li & 3) * 128;
    sHb[tid] = LDC(&hw[(size_t)bb*HH + tid]);
    __syncthreads();
    if (tid < 128){
      int col = c0 + tid;
      float a0 = 0.f;
      #pragma unroll 8
      for (int k = 0; k < 512; k++)
        a0 += Wkey[(size_t)k*HH + col] * sHb[k];
      STC(&qt[(size_t)bb*HH + col], a0);
    }
  };

  auto phaseC = [&](){
    if (tid < 8){ int l = slen[sMap[tid]]; if(l<1)l=1; if(l>LL)l=LL; sLen[tid]=l; }
    __syncthreads();
    if (tid == 0){
      sPref[0] = 0;
      for (int i=0;i<8;i++) sPref[i+1] = sPref[i] + (sLen[i]+CH-1)/CH;
    }
    __syncthreads();
    const int gTot = sPref[8];
    const int w = tid >> 6, lane = tid & 63;
    const float SCALE = 1.0f / sqrtf(512.0f);
    const int start = (li*gTot)/GBLK, end = ((li+1)*gTot)/GBLK;
    int b = 0, bLast = -1;
    for (int c = start; c < end; ++c){
      while (sPref[b+1] <= c) b++;
      int slot = c - sPref[b];
      int l0 = slot * CH;
      int lend = min(l0 + CH, sLen[b]);
      int bb = sMap[b];
      if (b != bLast){
        __syncthreads();
        sQt[tid] = LDC(&qt[(size_t)bb*HH + tid]);
        bLast = b;
      }
      __syncthreads();
      const float4* qp = (const float4*)sQt;
      float4 qa = qp[lane], qb = qp[64+lane];
      float m = -FLT_MAX, ss = 0.f;
      float4 aA = make_float4(0,0,0,0), aB = make_float4(0,0,0,0);
      for (int ls = l0; ls < lend; ls += 64){
        float4 ra[8], rb[8];
        #pragma unroll
        for (int d=0; d<8; d++){
          int row = ls + w + d*8;
          if (row < lend){
            const float4* rp = (const float4*)(seq + ((size_t)bb*LL + row)*HH);
            ra[d] = rp[lane]; rb[d] = rp[64+lane];
          }
        }
        #pragma unroll
        for (int d=0; d<8; d++){
          int row = ls + w + d*8;
          if (row < lend){
            float4 ea = ra[d], eb = rb[d];
            float dd = ea.x*qa.x + ea.y*qa.y + ea.z*qa.z + ea.w*qa.w
                     + eb.x*qb.x + eb.y*qb.y + eb.z*qb.z + eb.w*qb.w;
            #pragma unroll
            for (int msk=1; msk<64; msk<<=1) dd += __shfl_xor(dd, msk, 64);
            float sc = dd * SCALE;
            float mn = fmaxf(m, sc);
            float r1 = expf(m - mn);
            float w1 = expf(sc - mn);
            ss = ss*r1 + w1;
            aA.x = aA.x*r1 + w1*ea.x; aA.y = aA.y*r1 + w1*ea.y;
            aA.z = aA.z*r1 + w1*ea.z; aA.w = aA.w*r1 + w1*ea.w;
            aB.x = aB.x*r1 + w1*eb.x; aB.y = aB.y*r1 + w1*eb.y;
            aB.z = aB.z*r1 + w1*eb.z; aB.w = aB.w*r1 + w1*eb.w;
            m = mn;
          }
        }
      }
      ((float4*)(sAcc + w*512))[lane]    = aA;
      ((float4*)(sAcc + w*512))[64+lane] = aB;
      if (lane == 0){ sWm[w] = m; sWs[w] = ss; }
      __syncthreads();
      if (tid == 0){
        float M = sWm[0];
        #pragma unroll
        for (int i=1;i<8;i++) M = fmaxf(M, sWm[i]);
        float S = 0.f;
        #pragma unroll
        for (int i=0;i<8;i++){ float f = expf(sWm[i]-M); sWf[i]=f; S += sWs[i]*f; }
        STC(&pm[bb*MS+slot], M); STC(&ps[bb*MS+slot], S);
      }
      __syncthreads();
      {
        float v = 0.f;
        #pragma unroll
        for (int i=0;i<8;i++) v += sAcc[i*512 + tid] * sWf[i];
        STC(&pacc[((size_t)(bb*MS+slot))*HH + tid], v);
      }
    }
  };

  auto phaseD = [&](int t, const float* hw){
    if (li < 8){
      const int bb = sMap[li];
      int ln = slen[bb]; if(ln<1)ln=1; if(ln>LL)ln=LL;
      const int nsl = (ln + CH - 1)/CH;
      if (tid < nsl){ sAm[tid] = LDC(&pm[bb*MS + tid]); sAs[tid] = LDC(&ps[bb*MS + tid]); }
      __syncthreads();
      if (tid == 0){
        float M = sAm[0];
        for (int s=1;s<nsl;s++) M = fmaxf(M, sAm[s]);
        float S = 0.f;
        for (int s=0;s<nsl;s++){ float f = expf(sAm[s]-M); sAf[s] = f; S += sAs[s]*f; }
        sSc[0] = S;
      }
      __syncthreads();
      {
        float S = sSc[0];
        float v = 0.f;
        #pragma unroll 8
        for (int s=0;s<nsl;s++) v += LDC(&pacc[((size_t)(bb*MS+s))*HH + tid]) * sAf[s];
        sEb[tid] = v / S;
        sHs[tid] = LDC(&hw[(size_t)bb*HH + tid]);
      }
      __syncthreads();
      {
        const float4* wr = (const float4*)(Wval + (size_t)tid*HH);
        const float4* er = (const float4*)sEb;
        float a = bval[tid];
        #pragma unroll 8
        for (int i=0;i<HH/4;i++){
          float4 w4 = wr[i], e4 = er[i];
          a += w4.x*e4.x; a += w4.y*e4.y; a += w4.z*e4.z; a += w4.w*e4.w;
        }
        sCt[tid] = a;
        STC(&ctx[(size_t)bb*HH + tid], a);
      }
      __syncthreads();
      if (t >= 0){
        if (tid < 34*8){
          int v = tid >> 3, ks = tid & 7;
          const float* wr = Wcdn + (size_t)v*1024 + ks*128;
          const float* xr = (ks < 4) ? (sHs + ks*128) : (sCt + (ks-4)*128);
          float p = 0.f;
          #pragma unroll 8
          for (int i=0;i<128;i++) p += wr[i]*xr[i];
          sP[v*8+ks] = p;
        }
        __syncthreads();
        if (tid < 34){
          float lg = bcdn[tid];
          #pragma unroll
          for (int i=0;i<8;i++) lg += sP[tid*8+i];
          sZ[tid] = lg;
        }
        __syncthreads();
        gumbel_emit_(tid, bb, t, sZ, yv, out);
      }
    }
  };

  // ================= schedule: group-local, 4 group barriers per step =================
  gbar();
  phaseC();                 // qt == 0 -> uniform weights over valid positions
  gbar();
  phaseD(-1, h0);           // ebar/ctx only, no sampling
  gbar();
  measure = true;
  for (int t = 0; t < TT; t++){
    const float* hr = (t & 1) ? h1 : h0;
    float* hwv      = (t & 1) ? h0 : h1;
    phaseA(hr, hwv);
    gbar();
    phaseB(hwv);
    gbar();
    phaseC();
    gbar();
    phaseD(t, hwv);
    gbar();
  }

  // ================= exfiltrate barrier-wait via WRITE_SIZE =================
  // After the loop's final gbar, this group's blocks are all past D(599); pacc
  // rows of THIS group's batches are dead. Emit wtick bytes of contiguous
  // coherent stores into batch sMap[0]'s pacc region (256 KB window, wraps).
  if (tid == 0) sWT = wtick;
  __syncthreads();
  {
    ull nb = sWT;
    if (nb > (ull)(64u<<20)) nb = (ull)(64u<<20);   // cap 64 MB/block
    unsigned nst = (unsigned)(nb >> 2);             // 4B stores; bytes = wtick
    float* sink = pacc + (size_t)sMap[0]*MS*HH;     // MS*HH = 16384 floats (MS=32)
    unsigned mask = (unsigned)(MS*HH - 1);          // power of two for MS in {1..32}
    for (unsigned i = tid; i < nst; i += BLKT)
      STC(&sink[i & mask], 1.0f);
  }
}

extern "C" void kernel_launch(void* const* d_in, const int* in_sizes, int n_in,
                              void* d_out, int out_size, void* d_ws, size_t ws_size,
                              hipStream_t stream)
{
  const float* seq  = (const float*)d_in[0];
  const int*   slen = (const int*)d_in[1];
  const float* Ech  = (const float*)d_in[2];
  const float* Wkey = (const float*)d_in[3];
  // d_in[4] = b_key: cancels inside softmax, unused.
  const float* Wval = (const float*)d_in[5];
  const float* bval = (const float*)d_in[6];
  const float* Wih  = (const float*)d_in[7];
  const float* Whh  = (const float*)d_in[8];
  const float* bih  = (const float*)d_in[9];
  const float* bhh  = (const float*)d_in[10];
  const float* Wcdn = (const float*)d_in[11];
  const float* bcdn = (const float*)d_in[12];
  int*   out = (int*)d_out;
  float* ws  = (float*)d_ws;

  // IMPORTANT: identical need-formula to verified R13/R14 (MS must stay 32;
  // ws_size is tight: ~4.75-5.0 MB per R12 post-mortem).
  int MS = 32;
  size_t floats_total;
  while (true){
    floats_total = 4*(size_t)NB*HH + (size_t)NB*MS*(2 + HH);
    size_t need = (floats_total + 64 + 8*BSTRIDE + 64)*4;
    if (need <= ws_size || MS == 1) break;
    MS >>= 1;
  }
  int CH = 2048 / MS;

  size_t bar_off = (floats_total + 64)*4;
  hipMemsetAsync((char*)d_ws + bar_off, 0, 8*BSTRIDE*4, stream);

  void* args[] = { (void*)&seq, (void*)&slen, (void*)&Ech, (void*)&Wkey,
                   (void*)&Wval, (void*)&bval, (void*)&Wih, (void*)&Whh,
                   (void*)&bih, (void*)&bhh, (void*)&Wcdn, (void*)&bcdn,
                   (void*)&out, (void*)&ws, (void*)&MS, (void*)&CH };

  hipLaunchCooperativeKernel((void*)speller_kernel_g32, dim3(GRID), dim3(BLKT),
                             args, 0, stream);
}

// Round 16
// 71002.332 us; speedup vs baseline: 1.1527x; 1.1527x over previous
//
#include <hip/hip_runtime.h>
#include <cstdint>
#include <cfloat>
#include <cmath>

#define NB 64
#define LL 2048
#define HH 512
#define VV 34
#define TT 600
#define BLKT 512
#define GRID 256
#define GBLK 32     // blocks per group
#define BSTRIDE 544 // per-group barrier region (ints): 32 arrival slots x16 + release

// JAX threefry_partitionable (default since jax 0.4.36): bits = o0 ^ o1. VERIFIED round 2.
#define PARTITIONABLE 1

// Coherence-point (cross-XCD-safe) data path: bypasses L1/L2; no fences needed.
#define LDC(p)    __hip_atomic_load((p), __ATOMIC_RELAXED, __HIP_MEMORY_SCOPE_AGENT)
#define STC(p,v)  __hip_atomic_store((p), (v), __ATOMIC_RELAXED, __HIP_MEMORY_SCOPE_AGENT)

__device__ __forceinline__ float sigm_(float x){ return 1.0f/(1.0f+expf(-x)); }
__device__ __forceinline__ unsigned rotl_(unsigned x, int r){ return (x<<r)|(x>>(32-r)); }

// Threefry-2x32, 20 rounds, exactly JAX's schedule.
__device__ __forceinline__ void tf2x32_(unsigned k0, unsigned k1, unsigned x0, unsigned x1,
                                        unsigned &o0, unsigned &o1){
  unsigned ks2 = k0 ^ k1 ^ 0x1BD11BDAu;
  x0 += k0; x1 += k1;
  x0+=x1; x1=rotl_(x1,13); x1^=x0;
  x0+=x1; x1=rotl_(x1,15); x1^=x0;
  x0+=x1; x1=rotl_(x1,26); x1^=x0;
  x0+=x1; x1=rotl_(x1, 6); x1^=x0;
  x0+=k1; x1+=ks2+1u;
  x0+=x1; x1=rotl_(x1,17); x1^=x0;
  x0+=x1; x1=rotl_(x1,29); x1^=x0;
  x0+=x1; x1=rotl_(x1,16); x1^=x0;
  x0+=x1; x1=rotl_(x1,24); x1^=x0;
  x0+=ks2; x1+=k0+2u;
  x0+=x1; x1=rotl_(x1,13); x1^=x0;
  x0+=x1; x1=rotl_(x1,15); x1^=x0;
  x0+=x1; x1=rotl_(x1,26); x1^=x0;
  x0+=x1; x1=rotl_(x1, 6); x1^=x0;
  x0+=k0; x1+=k1+3u;
  x0+=x1; x1=rotl_(x1,17); x1^=x0;
  x0+=x1; x1=rotl_(x1,29); x1^=x0;
  x0+=x1; x1=rotl_(x1,16); x1^=x0;
  x0+=x1; x1=rotl_(x1,24); x1^=x0;
  x0+=k1; x1+=ks2+4u;
  x0+=x1; x1=rotl_(x1,13); x1^=x0;
  x0+=x1; x1=rotl_(x1,15); x1^=x0;
  x0+=x1; x1=rotl_(x1,26); x1^=x0;
  x0+=x1; x1=rotl_(x1, 6); x1^=x0;
  x0+=ks2; x1+=k0+5u;
  o0 = x0; o1 = x1;
}

// Gumbel sample + argmax write. tid<34 path.
__device__ __forceinline__ void gumbel_emit_(int tid, int bb, int t, float* sZ,
                                             int* yv, int* out){
  if (tid < 34){
    unsigned kk0, kk1; tf2x32_(0u, 42u, 0u, (unsigned)t, kk0, kk1);
    int idx = bb*34 + tid;
    unsigned o0, o1, bits;
#if PARTITIONABLE
    tf2x32_(kk0, kk1, 0u, (unsigned)idx, o0, o1);
    bits = o0 ^ o1;
#else
    if (idx < 1088){ tf2x32_(kk0, kk1, (unsigned)idx, (unsigned)(idx+1088), o0, o1); bits = o0; }
    else           { tf2x32_(kk0, kk1, (unsigned)(idx-1088), (unsigned)idx, o0, o1); bits = o1; }
#endif
    float f = __uint_as_float((bits>>9) | 0x3f800000u) - 1.0f;
    float u = fmaxf(f, 1.17549435e-38f);
    sZ[tid] += -logf(-logf(u));
  }
  __syncthreads();
  if (tid == 0){
    float best = sZ[0]; int bi = 0;
    for (int v2=1; v2<34; v2++){ if (sZ[v2] > best){ best = sZ[v2]; bi = v2; } }
    STC(&yv[bb], bi);
    STC(&out[bb*TT + t], bi);
  }
}

// ============================================================================
// Verified R14 kernel (grid 256, 32/group, LPT, leader-poll barrier)
// + LDS-staged bit-exact phaseB (fixes 2-wave latency-exposed serial B)
// ============================================================================
__global__ __launch_bounds__(BLKT, 2) void speller_kernel_g32(
    const float* __restrict__ seq, const int* __restrict__ slen,
    const float* __restrict__ Ech, const float* __restrict__ Wkey,
    const float* __restrict__ Wval, const float* __restrict__ bval,
    const float* __restrict__ Wih, const float* __restrict__ Whh,
    const float* __restrict__ bih, const float* __restrict__ bhh,
    const float* __restrict__ Wcdn, const float* __restrict__ bcdn,
    int* __restrict__ out, float* __restrict__ ws, int MS, int CH)
{
  const int tid = threadIdx.x;
  const int bid = blockIdx.x;
  const int grp = bid & 7;         // group ~ XCD round-robin (perf heuristic only)
  const int li  = bid >> 3;        // 0..31

  float* h0   = ws;
  float* h1   = h0 + NB*HH;
  float* qt   = h1 + NB*HH;
  float* ctx  = qt + NB*HH;
  float* pm   = ctx + NB*HH;
  float* ps   = pm + NB*MS;
  float* pacc = ps + NB*MS;
  int*   iw   = (int*)(pacc + (size_t)NB*MS*HH);
  int*   yv   = iw;                 // [64]
  int*   bar  = iw + 64;            // [8*BSTRIDE] zeroed per launch

  __shared__ float sX[24*516];
  __shared__ float sRed[8*8*64];
  __shared__ float sGate[512];
  __shared__ float sAcc[8*512];
  __shared__ float sQt[512];
  __shared__ float sHb[512];
  __shared__ float sWm[8], sWs[8], sWf[8];
  __shared__ float sEb[512], sHs[512], sCt[512];
  __shared__ float sP[34*8];
  __shared__ float sZ[34];
  __shared__ float sAm[32], sAs[32], sAf[32];
  __shared__ float sSc[2];
  __shared__ int   sYv[8], sLen[8], sPref[9], sMap[8];

  float creg = 0.f;
  int epoch = 0;

  // ---- RMW-free leader-poll group barrier (verified R14/R15) ----
  auto gbar = [&](){
    __syncthreads();
    epoch++;
    if (tid == 0)
      STC(&bar[grp*BSTRIDE + li*16], epoch);
    if (li == 0){
      if (tid < 32){
        while (LDC(&bar[grp*BSTRIDE + tid*16]) < epoch)
          __builtin_amdgcn_s_sleep(1);
      }
      if (tid == 0)
        STC(&bar[grp*BSTRIDE + 512], epoch);   // release word
    } else {
      if (tid == 0){
        while (LDC(&bar[grp*BSTRIDE + 512]) < epoch)
          __builtin_amdgcn_s_sleep(1);
      }
    }
    __syncthreads();
  };

  // ---- deterministic LPT batch->group assignment (capacity 8), per-block redundant ----
  if (tid == 0){
    int ln[64]; unsigned char used[64];
    int load[8], cnt[8];
    for (int i=0;i<64;i++){
      int l = slen[i]; if (l<1) l=1; if (l>LL) l=LL;
      ln[i] = l; used[i] = 0;
    }
    for (int g2=0; g2<8; g2++){ load[g2]=0; cnt[g2]=0; }
    for (int it=0; it<64; it++){
      int bi = -1, bl = -1;
      for (int i=0;i<64;i++) if (!used[i] && ln[i] > bl){ bl = ln[i]; bi = i; }
      used[bi] = 1;
      int gi = -1, gl = 0x7fffffff;
      for (int g2=0; g2<8; g2++) if (cnt[g2] < 8 && load[g2] < gl){ gl = load[g2]; gi = g2; }
      if (gi == grp) sMap[cnt[gi]] = bi;
      load[gi] += bl; cnt[gi]++;
    }
  }
  __syncthreads();

  // ---- group-local init ----
  if (li < 8){
    int bb = sMap[li];
    STC(&h0[(size_t)bb*HH + tid], 0.f);
    STC(&h1[(size_t)bb*HH + tid], 0.f);
    STC(&qt[(size_t)bb*HH + tid], 0.f);
  }
  if (li == 8 && tid < 8) STC(&yv[sMap[tid]], 0);   // SOS

  // ================= phases (FP order bit-exact vs verified R10/R13/R14) =================

  auto phaseA = [&](const float* hr, float* hw){
    if (tid < 8) sYv[tid] = LDC(&yv[sMap[tid]]);
    __syncthreads();
    #pragma unroll
    for (int i = 0; i < 24; i++){
      int b = i & 7, s = i >> 3;
      int bb = sMap[b];
      float v;
      if (s == 0)      v = Ech[(size_t)sYv[b]*HH + tid];
      else if (s == 1) v = LDC(&ctx[(size_t)bb*HH + tid]);
      else             v = LDC(&hr[(size_t)bb*HH + tid]);
      sX[i*516 + tid] = v;
    }
    __syncthreads();
    const int w = tid >> 6, lane = tid & 63, rr = lane >> 3, bb = lane & 7;
    float acc[8];
    #pragma unroll
    for (int o=0;o<8;o++) acc[o]=0.f;
    for (int kt = 0; kt < 12; kt++){
      const int sec = (kt < 4) ? 0 : (kt < 8) ? 1 : 2;
      const int cb4 = (kt & 3) * 128;
      #pragma unroll
      for (int it = 0; it < 4; it++){
        int kkb = w*16 + it*4;
        const float* xp = &sX[(sec*8 + bb)*516 + cb4 + kkb];
        float x0 = xp[0], x1 = xp[1], x2 = xp[2], x3 = xp[3];
        #pragma unroll
        for (int o = 0; o < 8; o++){
          int jl = o*8 + rr;
          int j  = (jl >> 4)*512 + li*16 + (jl & 15);
          const float* wp = (kt < 8) ? Wih + (size_t)j*1024 + kt*128 + kkb
                                     : Whh + (size_t)j*512  + (kt-8)*128 + kkb;
          float4 wv = *(const float4*)wp;
          acc[o] += wv.x*x0; acc[o] += wv.y*x1;
          acc[o] += wv.z*x2; acc[o] += wv.w*x3;
        }
      }
    }
    __syncthreads();
    #pragma unroll
    for (int o=0;o<8;o++) sRed[(w*8+o)*64 + lane] = acc[o];
    __syncthreads();
    {
      int jl = tid >> 3, b2 = tid & 7;
      int o = jl >> 3, rr2 = jl & 7;
      int j = (jl >> 4)*512 + li*16 + (jl & 15);
      float g = bih[j] + bhh[j];
      #pragma unroll
      for (int w2 = 0; w2 < 8; w2++) g += sRed[(w2*8+o)*64 + rr2*8 + b2];
      sGate[jl*8 + b2] = g;
    }
    __syncthreads();
    if (tid < 128){
      int kp = tid >> 3, b3 = tid & 7;
      float gi = sGate[(0*16+kp)*8 + b3];
      float gf = sGate[(1*16+kp)*8 + b3];
      float gg = sGate[(2*16+kp)*8 + b3];
      float go = sGate[(3*16+kp)*8 + b3];
      float cn = sigm_(gf)*creg + sigm_(gi)*tanhf(gg);
      creg = cn;
      STC(&hw[(size_t)sMap[b3]*HH + li*16 + kp], sigm_(go)*tanhf(cn));
    }
  };

  // B: qt[b][col] = sum_k Wkey[k][col]*h[b][k].
  // NEW: LDS-staged, all-512-thread staging, bit-exact accumulation.
  // Block li: cols [cc*64, cc*64+64) with cc=li&7; batches {2bp, 2bp+1} with bp=li>>3.
  // Per (col,batch): ONE thread accumulates k=0..511 sequentially with a single
  // accumulator -> identical FP sequence to the verified serial B.
  auto phaseB = [&](const float* hw){
    const int cc = li & 7;
    const int bp = li >> 3;
    const int bb0 = sMap[2*bp], bb1 = sMap[2*bp+1];
    // stage both h vectors (coherent)
    sHb[tid] = LDC(&hw[(size_t)bb0*HH + tid]);
    sQt[tid] = LDC(&hw[(size_t)bb1*HH + tid]);
    float a = 0.f;                      // accumulator for this thread's (col,batch) dot
    const int c  = tid & 63;            // col within chunk (threads 0..127 accumulate)
    const int bs = (tid >> 6) & 1;      // batch select
    for (int tile = 0; tile < 4; tile++){
      const int k0 = tile * 128;
      __syncthreads();                  // previous accumulate done (and h staged, tile 0)
      // stage Wkey[k0..k0+127][cc*64 .. cc*64+64) -> sX[kk*64 + c] (32 KB)
      {
        const float4* src = (const float4*)(Wkey + (size_t)k0*HH + cc*64);
        float4* dst = (float4*)sX;
        // 128 rows x 16 float4; row stride HH/4 float4s
        #pragma unroll
        for (int r = 0; r < 4; r++){
          int idx = r*512 + tid;        // 0..2047
          int kk = idx >> 4, c4 = idx & 15;
          dst[kk*16 + c4] = src[(size_t)kk*(HH/4) + c4];
        }
      }
      __syncthreads();
      if (tid < 128){
        const float* hv = bs ? sQt : sHb;
        // sequential k within tile; tiles in order -> overall k=0..511 in order
        for (int kk = 0; kk < 128; kk++)
          a += sX[kk*64 + c] * hv[k0 + kk];
      }
    }
    __syncthreads();
    if (tid < 128){
      int bbX = bs ? bb1 : bb0;
      STC(&qt[(size_t)bbX*HH + cc*64 + c], a);
    }
  };

  auto phaseC = [&](){
    if (tid < 8){ int l = slen[sMap[tid]]; if(l<1)l=1; if(l>LL)l=LL; sLen[tid]=l; }
    __syncthreads();
    if (tid == 0){
      sPref[0] = 0;
      for (int i=0;i<8;i++) sPref[i+1] = sPref[i] + (sLen[i]+CH-1)/CH;
    }
    __syncthreads();
    const int gTot = sPref[8];
    const int w = tid >> 6, lane = tid & 63;
    const float SCALE = 1.0f / sqrtf(512.0f);
    const int start = (li*gTot)/GBLK, end = ((li+1)*gTot)/GBLK;
    int b = 0, bLast = -1;
    for (int c = start; c < end; ++c){
      while (sPref[b+1] <= c) b++;
      int slot = c - sPref[b];
      int l0 = slot * CH;
      int lend = min(l0 + CH, sLen[b]);
      int bb = sMap[b];
      if (b != bLast){
        __syncthreads();
        sQt[tid] = LDC(&qt[(size_t)bb*HH + tid]);
        bLast = b;
      }
      __syncthreads();
      const float4* qp = (const float4*)sQt;
      float4 qa = qp[lane], qb = qp[64+lane];
      float m = -FLT_MAX, ss = 0.f;
      float4 aA = make_float4(0,0,0,0), aB = make_float4(0,0,0,0);
      for (int ls = l0; ls < lend; ls += 64){
        float4 ra[8], rb[8];
        #pragma unroll
        for (int d=0; d<8; d++){
          int row = ls + w + d*8;
          if (row < lend){
            const float4* rp = (const float4*)(seq + ((size_t)bb*LL + row)*HH);
            ra[d] = rp[lane]; rb[d] = rp[64+lane];
          }
        }
        #pragma unroll
        for (int d=0; d<8; d++){
          int row = ls + w + d*8;
          if (row < lend){
            float4 ea = ra[d], eb = rb[d];
            float dd = ea.x*qa.x + ea.y*qa.y + ea.z*qa.z + ea.w*qa.w
                     + eb.x*qb.x + eb.y*qb.y + eb.z*qb.z + eb.w*qb.w;
            #pragma unroll
            for (int msk=1; msk<64; msk<<=1) dd += __shfl_xor(dd, msk, 64);
            float sc = dd * SCALE;
            float mn = fmaxf(m, sc);
            float r1 = expf(m - mn);
            float w1 = expf(sc - mn);
            ss = ss*r1 + w1;
            aA.x = aA.x*r1 + w1*ea.x; aA.y = aA.y*r1 + w1*ea.y;
            aA.z = aA.z*r1 + w1*ea.z; aA.w = aA.w*r1 + w1*ea.w;
            aB.x = aB.x*r1 + w1*eb.x; aB.y = aB.y*r1 + w1*eb.y;
            aB.z = aB.z*r1 + w1*eb.z; aB.w = aB.w*r1 + w1*eb.w;
            m = mn;
          }
        }
      }
      ((float4*)(sAcc + w*512))[lane]    = aA;
      ((float4*)(sAcc + w*512))[64+lane] = aB;
      if (lane == 0){ sWm[w] = m; sWs[w] = ss; }
      __syncthreads();
      if (tid == 0){
        float M = sWm[0];
        #pragma unroll
        for (int i=1;i<8;i++) M = fmaxf(M, sWm[i]);
        float S = 0.f;
        #pragma unroll
        for (int i=0;i<8;i++){ float f = expf(sWm[i]-M); sWf[i]=f; S += sWs[i]*f; }
        STC(&pm[bb*MS+slot], M); STC(&ps[bb*MS+slot], S);
      }
      __syncthreads();
      {
        float v = 0.f;
        #pragma unroll
        for (int i=0;i<8;i++) v += sAcc[i*512 + tid] * sWf[i];
        STC(&pacc[((size_t)(bb*MS+slot))*HH + tid], v);
      }
    }
  };

  auto phaseD = [&](int t, const float* hw){
    if (li < 8){
      const int bb = sMap[li];
      int ln = slen[bb]; if(ln<1)ln=1; if(ln>LL)ln=LL;
      const int nsl = (ln + CH - 1)/CH;
      if (tid < nsl){ sAm[tid] = LDC(&pm[bb*MS + tid]); sAs[tid] = LDC(&ps[bb*MS + tid]); }
      __syncthreads();
      if (tid == 0){
        float M = sAm[0];
        for (int s=1;s<nsl;s++) M = fmaxf(M, sAm[s]);
        float S = 0.f;
        for (int s=0;s<nsl;s++){ float f = expf(sAm[s]-M); sAf[s] = f; S += sAs[s]*f; }
        sSc[0] = S;
      }
      __syncthreads();
      {
        float S = sSc[0];
        float v = 0.f;
        #pragma unroll 8
        for (int s=0;s<nsl;s++) v += LDC(&pacc[((size_t)(bb*MS+s))*HH + tid]) * sAf[s];
        sEb[tid] = v / S;
        sHs[tid] = LDC(&hw[(size_t)bb*HH + tid]);
      }
      __syncthreads();
      {
        const float4* wr = (const float4*)(Wval + (size_t)tid*HH);
        const float4* er = (const float4*)sEb;
        float a = bval[tid];
        #pragma unroll 8
        for (int i=0;i<HH/4;i++){
          float4 w4 = wr[i], e4 = er[i];
          a += w4.x*e4.x; a += w4.y*e4.y; a += w4.z*e4.z; a += w4.w*e4.w;
        }
        sCt[tid] = a;
        STC(&ctx[(size_t)bb*HH + tid], a);
      }
      __syncthreads();
      if (t >= 0){
        if (tid < 34*8){
          int v = tid >> 3, ks = tid & 7;
          const float* wr = Wcdn + (size_t)v*1024 + ks*128;
          const float* xr = (ks < 4) ? (sHs + ks*128) : (sCt + (ks-4)*128);
          float p = 0.f;
          #pragma unroll 8
          for (int i=0;i<128;i++) p += wr[i]*xr[i];
          sP[v*8+ks] = p;
        }
        __syncthreads();
        if (tid < 34){
          float lg = bcdn[tid];
          #pragma unroll
          for (int i=0;i<8;i++) lg += sP[tid*8+i];
          sZ[tid] = lg;
        }
        __syncthreads();
        gumbel_emit_(tid, bb, t, sZ, yv, out);
      }
    }
  };

  // ================= schedule: group-local, 4 group barriers per step =================
  gbar();
  phaseC();                 // qt == 0 -> uniform weights over valid positions
  gbar();
  phaseD(-1, h0);           // ebar/ctx only, no sampling
  gbar();
  for (int t = 0; t < TT; t++){
    const float* hr = (t & 1) ? h1 : h0;
    float* hwv      = (t & 1) ? h0 : h1;
    phaseA(hr, hwv);
    gbar();
    phaseB(hwv);
    gbar();
    phaseC();
    gbar();
    phaseD(t, hwv);
    gbar();
  }
}

extern "C" void kernel_launch(void* const* d_in, const int* in_sizes, int n_in,
                              void* d_out, int out_size, void* d_ws, size_t ws_size,
                              hipStream_t stream)
{
  const float* seq  = (const float*)d_in[0];
  const int*   slen = (const int*)d_in[1];
  const float* Ech  = (const float*)d_in[2];
  const float* Wkey = (const float*)d_in[3];
  // d_in[4] = b_key: cancels inside softmax, unused.
  const float* Wval = (const float*)d_in[5];
  const float* bval = (const float*)d_in[6];
  const float* Wih  = (const float*)d_in[7];
  const float* Whh  = (const float*)d_in[8];
  const float* bih  = (const float*)d_in[9];
  const float* bhh  = (const float*)d_in[10];
  const float* Wcdn = (const float*)d_in[11];
  const float* bcdn = (const float*)d_in[12];
  int*   out = (int*)d_out;
  float* ws  = (float*)d_ws;

  // IMPORTANT: identical need-formula to verified R13/R14/R15 (MS must stay 32;
  // ws_size is tight: ~4.75-5.0 MB per R12 post-mortem).
  int MS = 32;
  size_t floats_total;
  while (true){
    floats_total = 4*(size_t)NB*HH + (size_t)NB*MS*(2 + HH);
    size_t need = (floats_total + 64 + 8*BSTRIDE + 64)*4;
    if (need <= ws_size || MS == 1) break;
    MS >>= 1;
  }
  int CH = 2048 / MS;

  size_t bar_off = (floats_total + 64)*4;
  hipMemsetAsync((char*)d_ws + bar_off, 0, 8*BSTRIDE*4, stream);

  void* args[] = { (void*)&seq, (void*)&slen, (void*)&Ech, (void*)&Wkey,
                   (void*)&Wval, (void*)&bval, (void*)&Wih, (void*)&Whh,
                   (void*)&bih, (void*)&bhh, (void*)&Wcdn, (void*)&bcdn,
                   (void*)&out, (void*)&ws, (void*)&MS, (void*)&CH };

  hipLaunchCooperativeKernel((void*)speller_kernel_g32, dim3(GRID), dim3(BLKT),
                             args, 0, stream);
}

// Round 17
// 62010.809 us; speedup vs baseline: 1.3198x; 1.1450x over previous
//
#include <hip/hip_runtime.h>
#include <cstdint>
#include <cfloat>
#include <cmath>

#define NB 64
#define LL 2048
#define HH 512
#define VV 34
#define TT 600
#define BLKT 512
#define GRID 256
#define GBLK 32     // blocks per group
#define BSTRIDE 544 // per-group barrier region (ints): 32 arrival slots x16 (+pad)

// JAX threefry_partitionable (default since jax 0.4.36): bits = o0 ^ o1. VERIFIED round 2.
#define PARTITIONABLE 1

// Coherence-point (cross-XCD-safe) data path: bypasses L1/L2; no fences needed.
#define LDC(p)    __hip_atomic_load((p), __ATOMIC_RELAXED, __HIP_MEMORY_SCOPE_AGENT)
#define STC(p,v)  __hip_atomic_store((p), (v), __ATOMIC_RELAXED, __HIP_MEMORY_SCOPE_AGENT)

__device__ __forceinline__ float sigm_(float x){ return 1.0f/(1.0f+expf(-x)); }
__device__ __forceinline__ unsigned rotl_(unsigned x, int r){ return (x<<r)|(x>>(32-r)); }

// Threefry-2x32, 20 rounds, exactly JAX's schedule.
__device__ __forceinline__ void tf2x32_(unsigned k0, unsigned k1, unsigned x0, unsigned x1,
                                        unsigned &o0, unsigned &o1){
  unsigned ks2 = k0 ^ k1 ^ 0x1BD11BDAu;
  x0 += k0; x1 += k1;
  x0+=x1; x1=rotl_(x1,13); x1^=x0;
  x0+=x1; x1=rotl_(x1,15); x1^=x0;
  x0+=x1; x1=rotl_(x1,26); x1^=x0;
  x0+=x1; x1=rotl_(x1, 6); x1^=x0;
  x0+=k1; x1+=ks2+1u;
  x0+=x1; x1=rotl_(x1,17); x1^=x0;
  x0+=x1; x1=rotl_(x1,29); x1^=x0;
  x0+=x1; x1=rotl_(x1,16); x1^=x0;
  x0+=x1; x1=rotl_(x1,24); x1^=x0;
  x0+=ks2; x1+=k0+2u;
  x0+=x1; x1=rotl_(x1,13); x1^=x0;
  x0+=x1; x1=rotl_(x1,15); x1^=x0;
  x0+=x1; x1=rotl_(x1,26); x1^=x0;
  x0+=x1; x1=rotl_(x1, 6); x1^=x0;
  x0+=k0; x1+=k1+3u;
  x0+=x1; x1=rotl_(x1,17); x1^=x0;
  x0+=x1; x1=rotl_(x1,29); x1^=x0;
  x0+=x1; x1=rotl_(x1,16); x1^=x0;
  x0+=x1; x1=rotl_(x1,24); x1^=x0;
  x0+=k1; x1+=ks2+4u;
  x0+=x1; x1=rotl_(x1,13); x1^=x0;
  x0+=x1; x1=rotl_(x1,15); x1^=x0;
  x0+=x1; x1=rotl_(x1,26); x1^=x0;
  x0+=x1; x1=rotl_(x1, 6); x1^=x0;
  x0+=ks2; x1+=k0+5u;
  o0 = x0; o1 = x1;
}

// Gumbel sample + argmax write. tid<34 path.
__device__ __forceinline__ void gumbel_emit_(int tid, int bb, int t, float* sZ,
                                             int* yv, int* out){
  if (tid < 34){
    unsigned kk0, kk1; tf2x32_(0u, 42u, 0u, (unsigned)t, kk0, kk1);
    int idx = bb*34 + tid;
    unsigned o0, o1, bits;
#if PARTITIONABLE
    tf2x32_(kk0, kk1, 0u, (unsigned)idx, o0, o1);
    bits = o0 ^ o1;
#else
    if (idx < 1088){ tf2x32_(kk0, kk1, (unsigned)idx, (unsigned)(idx+1088), o0, o1); bits = o0; }
    else           { tf2x32_(kk0, kk1, (unsigned)(idx-1088), (unsigned)idx, o0, o1); bits = o1; }
#endif
    float f = __uint_as_float((bits>>9) | 0x3f800000u) - 1.0f;
    float u = fmaxf(f, 1.17549435e-38f);
    sZ[tid] += -logf(-logf(u));
  }
  __syncthreads();
  if (tid == 0){
    float best = sZ[0]; int bi = 0;
    for (int v2=1; v2<34; v2++){ if (sZ[v2] > best){ best = sZ[v2]; bi = v2; } }
    STC(&yv[bb], bi);
    STC(&out[bb*TT + t], bi);
  }
}

// ============================================================================
// R16 kernel + 32-block-parallel D (D1/D2/D3) + single-hop symmetric barrier
// ============================================================================
__global__ __launch_bounds__(BLKT, 2) void speller_kernel_g32(
    const float* __restrict__ seq, const int* __restrict__ slen,
    const float* __restrict__ Ech, const float* __restrict__ Wkey,
    const float* __restrict__ Wval, const float* __restrict__ bval,
    const float* __restrict__ Wih, const float* __restrict__ Whh,
    const float* __restrict__ bih, const float* __restrict__ bhh,
    const float* __restrict__ Wcdn, const float* __restrict__ bcdn,
    int* __restrict__ out, float* __restrict__ ws, int MS, int CH)
{
  const int tid = threadIdx.x;
  const int bid = blockIdx.x;
  const int grp = bid & 7;         // group ~ XCD round-robin (perf heuristic only)
  const int li  = bid >> 3;        // 0..31

  float* h0   = ws;
  float* h1   = h0 + NB*HH;
  float* qt   = h1 + NB*HH;
  float* ctx  = qt + NB*HH;
  float* pm   = ctx + NB*HH;
  float* ps   = pm + NB*MS;
  float* pacc = ps + NB*MS;
  int*   iw   = (int*)(pacc + (size_t)NB*MS*HH);
  int*   yv   = iw;                 // [64]
  int*   bar  = iw + 64;            // [8*BSTRIDE] zeroed per launch

  __shared__ float sX[24*516];
  __shared__ float sRed[8*8*64];
  __shared__ float sGate[512];
  __shared__ float sAcc[8*512];
  __shared__ float sQt[512];
  __shared__ float sHb[512];
  __shared__ float sWm[8], sWs[8], sWf[8];
  __shared__ float sEb[512], sHs[512], sCt[512];
  __shared__ float sP[34*8];
  __shared__ float sZ[34];
  __shared__ float sAm[32], sAs[32], sAf[32];
  __shared__ float sSc[2];
  __shared__ int   sYv[8], sLen[8], sPref[9], sMap[8];

  float creg = 0.f;
  int epoch = 0;

  // ---- single-hop symmetric group barrier: each block's wave0 polls all 32 slots ----
  // Ordering contract unchanged: __syncthreads drains vmcnt(0), so all data STCs
  // are coherence-point-visible before the arrival STC (verified R10-R16).
  auto gbar = [&](){
    __syncthreads();
    epoch++;
    if (tid == 0)
      STC(&bar[grp*BSTRIDE + li*16], epoch);
    if (tid < 32){
      while (LDC(&bar[grp*BSTRIDE + tid*16]) < epoch)
        __builtin_amdgcn_s_sleep(1);
    }
    __syncthreads();
  };

  // ---- deterministic LPT batch->group assignment (capacity 8), per-block redundant ----
  if (tid == 0){
    int ln[64]; unsigned char used[64];
    int load[8], cnt[8];
    for (int i=0;i<64;i++){
      int l = slen[i]; if (l<1) l=1; if (l>LL) l=LL;
      ln[i] = l; used[i] = 0;
    }
    for (int g2=0; g2<8; g2++){ load[g2]=0; cnt[g2]=0; }
    for (int it=0; it<64; it++){
      int bi = -1, bl = -1;
      for (int i=0;i<64;i++) if (!used[i] && ln[i] > bl){ bl = ln[i]; bi = i; }
      used[bi] = 1;
      int gi = -1, gl = 0x7fffffff;
      for (int g2=0; g2<8; g2++) if (cnt[g2] < 8 && load[g2] < gl){ gl = load[g2]; gi = g2; }
      if (gi == grp) sMap[cnt[gi]] = bi;
      load[gi] += bl; cnt[gi]++;
    }
  }
  __syncthreads();

  // ---- group-local init ----
  if (li < 8){
    int bb = sMap[li];
    STC(&h0[(size_t)bb*HH + tid], 0.f);
    STC(&h1[(size_t)bb*HH + tid], 0.f);
    STC(&qt[(size_t)bb*HH + tid], 0.f);
  }
  if (li == 8 && tid < 8) STC(&yv[sMap[tid]], 0);   // SOS

  // ================= phases (FP order bit-exact vs verified R16) =================

  auto phaseA = [&](const float* hr, float* hw){
    if (tid < 8) sYv[tid] = LDC(&yv[sMap[tid]]);
    __syncthreads();
    #pragma unroll
    for (int i = 0; i < 24; i++){
      int b = i & 7, s = i >> 3;
      int bb = sMap[b];
      float v;
      if (s == 0)      v = Ech[(size_t)sYv[b]*HH + tid];
      else if (s == 1) v = LDC(&ctx[(size_t)bb*HH + tid]);
      else             v = LDC(&hr[(size_t)bb*HH + tid]);
      sX[i*516 + tid] = v;
    }
    __syncthreads();
    const int w = tid >> 6, lane = tid & 63, rr = lane >> 3, bb = lane & 7;
    float acc[8];
    #pragma unroll
    for (int o=0;o<8;o++) acc[o]=0.f;
    for (int kt = 0; kt < 12; kt++){
      const int sec = (kt < 4) ? 0 : (kt < 8) ? 1 : 2;
      const int cb4 = (kt & 3) * 128;
      #pragma unroll
      for (int it = 0; it < 4; it++){
        int kkb = w*16 + it*4;
        const float* xp = &sX[(sec*8 + bb)*516 + cb4 + kkb];
        float x0 = xp[0], x1 = xp[1], x2 = xp[2], x3 = xp[3];
        #pragma unroll
        for (int o = 0; o < 8; o++){
          int jl = o*8 + rr;
          int j  = (jl >> 4)*512 + li*16 + (jl & 15);
          const float* wp = (kt < 8) ? Wih + (size_t)j*1024 + kt*128 + kkb
                                     : Whh + (size_t)j*512  + (kt-8)*128 + kkb;
          float4 wv = *(const float4*)wp;
          acc[o] += wv.x*x0; acc[o] += wv.y*x1;
          acc[o] += wv.z*x2; acc[o] += wv.w*x3;
        }
      }
    }
    __syncthreads();
    #pragma unroll
    for (int o=0;o<8;o++) sRed[(w*8+o)*64 + lane] = acc[o];
    __syncthreads();
    {
      int jl = tid >> 3, b2 = tid & 7;
      int o = jl >> 3, rr2 = jl & 7;
      int j = (jl >> 4)*512 + li*16 + (jl & 15);
      float g = bih[j] + bhh[j];
      #pragma unroll
      for (int w2 = 0; w2 < 8; w2++) g += sRed[(w2*8+o)*64 + rr2*8 + b2];
      sGate[jl*8 + b2] = g;
    }
    __syncthreads();
    if (tid < 128){
      int kp = tid >> 3, b3 = tid & 7;
      float gi = sGate[(0*16+kp)*8 + b3];
      float gf = sGate[(1*16+kp)*8 + b3];
      float gg = sGate[(2*16+kp)*8 + b3];
      float go = sGate[(3*16+kp)*8 + b3];
      float cn = sigm_(gf)*creg + sigm_(gi)*tanhf(gg);
      creg = cn;
      STC(&hw[(size_t)sMap[b3]*HH + li*16 + kp], sigm_(go)*tanhf(cn));
    }
  };

  // B: LDS-staged (verified R16). Block li: cols cc*64..cc*64+64, batches {2bp,2bp+1}.
  auto phaseB = [&](const float* hw){
    const int cc = li & 7;
    const int bp = li >> 3;
    const int bb0 = sMap[2*bp], bb1 = sMap[2*bp+1];
    sHb[tid] = LDC(&hw[(size_t)bb0*HH + tid]);
    sQt[tid] = LDC(&hw[(size_t)bb1*HH + tid]);
    float a = 0.f;
    const int c  = tid & 63;
    const int bs = (tid >> 6) & 1;
    for (int tile = 0; tile < 4; tile++){
      const int k0 = tile * 128;
      __syncthreads();
      {
        const float4* src = (const float4*)(Wkey + (size_t)k0*HH + cc*64);
        float4* dst = (float4*)sX;
        #pragma unroll
        for (int r = 0; r < 4; r++){
          int idx = r*512 + tid;
          int kk = idx >> 4, c4 = idx & 15;
          dst[kk*16 + c4] = src[(size_t)kk*(HH/4) + c4];
        }
      }
      __syncthreads();
      if (tid < 128){
        const float* hv = bs ? sQt : sHb;
        for (int kk = 0; kk < 128; kk++)
          a += sX[kk*64 + c] * hv[k0 + kk];
      }
    }
    __syncthreads();
    if (tid < 128){
      int bbX = bs ? bb1 : bb0;
      STC(&qt[(size_t)bbX*HH + cc*64 + c], a);
    }
  };

  auto phaseC = [&](){
    if (tid < 8){ int l = slen[sMap[tid]]; if(l<1)l=1; if(l>LL)l=LL; sLen[tid]=l; }
    __syncthreads();
    if (tid == 0){
      sPref[0] = 0;
      for (int i=0;i<8;i++) sPref[i+1] = sPref[i] + (sLen[i]+CH-1)/CH;
    }
    __syncthreads();
    const int gTot = sPref[8];
    const int w = tid >> 6, lane = tid & 63;
    const float SCALE = 1.0f / sqrtf(512.0f);
    const int start = (li*gTot)/GBLK, end = ((li+1)*gTot)/GBLK;
    int b = 0, bLast = -1;
    for (int c = start; c < end; ++c){
      while (sPref[b+1] <= c) b++;
      int slot = c - sPref[b];
      int l0 = slot * CH;
      int lend = min(l0 + CH, sLen[b]);
      int bb = sMap[b];
      if (b != bLast){
        __syncthreads();
        sQt[tid] = LDC(&qt[(size_t)bb*HH + tid]);
        bLast = b;
      }
      __syncthreads();
      const float4* qp = (const float4*)sQt;
      float4 qa = qp[lane], qb = qp[64+lane];
      float m = -FLT_MAX, ss = 0.f;
      float4 aA = make_float4(0,0,0,0), aB = make_float4(0,0,0,0);
      for (int ls = l0; ls < lend; ls += 64){
        float4 ra[8], rb[8];
        #pragma unroll
        for (int d=0; d<8; d++){
          int row = ls + w + d*8;
          if (row < lend){
            const float4* rp = (const float4*)(seq + ((size_t)bb*LL + row)*HH);
            ra[d] = rp[lane]; rb[d] = rp[64+lane];
          }
        }
        #pragma unroll
        for (int d=0; d<8; d++){
          int row = ls + w + d*8;
          if (row < lend){
            float4 ea = ra[d], eb = rb[d];
            float dd = ea.x*qa.x + ea.y*qa.y + ea.z*qa.z + ea.w*qa.w
                     + eb.x*qb.x + eb.y*qb.y + eb.z*qb.z + eb.w*qb.w;
            #pragma unroll
            for (int msk=1; msk<64; msk<<=1) dd += __shfl_xor(dd, msk, 64);
            float sc = dd * SCALE;
            float mn = fmaxf(m, sc);
            float r1 = expf(m - mn);
            float w1 = expf(sc - mn);
            ss = ss*r1 + w1;
            aA.x = aA.x*r1 + w1*ea.x; aA.y = aA.y*r1 + w1*ea.y;
            aA.z = aA.z*r1 + w1*ea.z; aA.w = aA.w*r1 + w1*ea.w;
            aB.x = aB.x*r1 + w1*eb.x; aB.y = aB.y*r1 + w1*eb.y;
            aB.z = aB.z*r1 + w1*eb.z; aB.w = aB.w*r1 + w1*eb.w;
            m = mn;
          }
        }
      }
      ((float4*)(sAcc + w*512))[lane]    = aA;
      ((float4*)(sAcc + w*512))[64+lane] = aB;
      if (lane == 0){ sWm[w] = m; sWs[w] = ss; }
      __syncthreads();
      if (tid == 0){
        float M = sWm[0];
        #pragma unroll
        for (int i=1;i<8;i++) M = fmaxf(M, sWm[i]);
        float S = 0.f;
        #pragma unroll
        for (int i=0;i<8;i++){ float f = expf(sWm[i]-M); sWf[i]=f; S += sWs[i]*f; }
        STC(&pm[bb*MS+slot], M); STC(&ps[bb*MS+slot], S);
      }
      __syncthreads();
      {
        float v = 0.f;
        #pragma unroll
        for (int i=0;i<8;i++) v += sAcc[i*512 + tid] * sWf[i];
        STC(&pacc[((size_t)(bb*MS+slot))*HH + tid], v);
      }
    }
  };

  // D1: ebar reduce, 32 blocks = 8 batches x 4 col-quarters. eb = dead h buffer.
  // Per-col FP order identical to verified R16 D (slot order s=0..nsl, v/S).
  auto phaseD1 = [&](float* eb){
    const int bq = li >> 2, qq = li & 3;
    const int bb = sMap[bq];
    int ln = slen[bb]; if(ln<1)ln=1; if(ln>LL)ln=LL;
    const int nsl = (ln + CH - 1)/CH;
    if (tid < nsl){ sAm[tid] = LDC(&pm[bb*MS + tid]); sAs[tid] = LDC(&ps[bb*MS + tid]); }
    __syncthreads();
    if (tid == 0){
      float M = sAm[0];
      for (int s=1;s<nsl;s++) M = fmaxf(M, sAm[s]);
      float S = 0.f;
      for (int s=0;s<nsl;s++){ float f = expf(sAm[s]-M); sAf[s] = f; S += sAs[s]*f; }
      sSc[0] = S;
    }
    __syncthreads();
    if (tid < 128){
      const int col = qq*128 + tid;
      const float S = sSc[0];
      float v = 0.f;
      #pragma unroll 8
      for (int s=0;s<nsl;s++) v += LDC(&pacc[((size_t)(bb*MS+s))*HH + col]) * sAf[s];
      STC(&eb[(size_t)bb*HH + col], v / S);
    }
  };

  // D2: ctx matvec, 32 blocks = 8 batches x 4 col-quarters.
  // Per-col FP order identical to verified R16 (float4 i=0..127).
  auto phaseD2 = [&](const float* eb){
    const int bq = li >> 2, qq = li & 3;
    const int bb = sMap[bq];
    sEb[tid] = LDC(&eb[(size_t)bb*HH + tid]);   // full ebar staged by 512 threads
    __syncthreads();
    if (tid < 128){
      const int col = qq*128 + tid;
      const float4* wr = (const float4*)(Wval + (size_t)col*HH);
      const float4* er = (const float4*)sEb;
      float a = bval[col];
      #pragma unroll 8
      for (int i=0;i<HH/4;i++){
        float4 w4 = wr[i], e4 = er[i];
        a += w4.x*e4.x; a += w4.y*e4.y; a += w4.z*e4.z; a += w4.w*e4.w;
      }
      STC(&ctx[(size_t)bb*HH + col], a);
    }
  };

  // D3: logits + gumbel sample, 8 blocks (li<8), one batch each.
  auto phaseD3 = [&](int t, const float* hw){
    if (li < 8){
      const int bb = sMap[li];
      sHs[tid] = LDC(&hw[(size_t)bb*HH + tid]);
      sCt[tid] = LDC(&ctx[(size_t)bb*HH + tid]);
      __syncthreads();
      if (tid < 34*8){
        int v = tid >> 3, ks = tid & 7;
        const float* wr = Wcdn + (size_t)v*1024 + ks*128;
        const float* xr = (ks < 4) ? (sHs + ks*128) : (sCt + (ks-4)*128);
        float p = 0.f;
        #pragma unroll 8
        for (int i=0;i<128;i++) p += wr[i]*xr[i];
        sP[v*8+ks] = p;
      }
      __syncthreads();
      if (tid < 34){
        float lg = bcdn[tid];
        #pragma unroll
        for (int i=0;i<8;i++) lg += sP[tid*8+i];
        sZ[tid] = lg;
      }
      __syncthreads();
      gumbel_emit_(tid, bb, t, sZ, yv, out);
    }
  };

  // ================= schedule: group-local, 6 single-hop barriers per step =================
  gbar();
  phaseC();                 // qt == 0 -> uniform weights over valid positions
  gbar();
  phaseD1(h1);              // ebar(-1) into h1 (dead: A(0) reads h0, writes h1)
  gbar();
  phaseD2(h1);              // ctx(-1); no sampling at t=-1
  gbar();
  for (int t = 0; t < TT; t++){
    const float* hr = (t & 1) ? h1 : h0;   // h(t-1): dead after C(t) -> ebar buffer
    float* hwv      = (t & 1) ? h0 : h1;   // h(t)
    phaseA(hr, hwv);
    gbar();
    phaseB(hwv);
    gbar();
    phaseC();
    gbar();
    phaseD1((float*)hr);
    gbar();
    phaseD2(hr);
    gbar();
    phaseD3(t, hwv);
    gbar();
  }
}

extern "C" void kernel_launch(void* const* d_in, const int* in_sizes, int n_in,
                              void* d_out, int out_size, void* d_ws, size_t ws_size,
                              hipStream_t stream)
{
  const float* seq  = (const float*)d_in[0];
  const int*   slen = (const int*)d_in[1];
  const float* Ech  = (const float*)d_in[2];
  const float* Wkey = (const float*)d_in[3];
  // d_in[4] = b_key: cancels inside softmax, unused.
  const float* Wval = (const float*)d_in[5];
  const float* bval = (const float*)d_in[6];
  const float* Wih  = (const float*)d_in[7];
  const float* Whh  = (const float*)d_in[8];
  const float* bih  = (const float*)d_in[9];
  const float* bhh  = (const float*)d_in[10];
  const float* Wcdn = (const float*)d_in[11];
  const float* bcdn = (const float*)d_in[12];
  int*   out = (int*)d_out;
  float* ws  = (float*)d_ws;

  // IMPORTANT: identical need-formula to verified R13-R16 (MS must stay 32;
  // ws_size is tight: ~4.75-5.0 MB per R12 post-mortem).
  int MS = 32;
  size_t floats_total;
  while (true){
    floats_total = 4*(size_t)NB*HH + (size_t)NB*MS*(2 + HH);
    size_t need = (floats_total + 64 + 8*BSTRIDE + 64)*4;
    if (need <= ws_size || MS == 1) break;
    MS >>= 1;
  }
  int CH = 2048 / MS;

  size_t bar_off = (floats_total + 64)*4;
  hipMemsetAsync((char*)d_ws + bar_off, 0, 8*BSTRIDE*4, stream);

  void* args[] = { (void*)&seq, (void*)&slen, (void*)&Ech, (void*)&Wkey,
                   (void*)&Wval, (void*)&bval, (void*)&Wih, (void*)&Whh,
                   (void*)&bih, (void*)&bhh, (void*)&Wcdn, (void*)&bcdn,
                   (void*)&out, (void*)&ws, (void*)&MS, (void*)&CH };

  hipLaunchCooperativeKernel((void*)speller_kernel_g32, dim3(GRID), dim3(BLKT),
                             args, 0, stream);
}